// Round 1
// baseline (34.623 us; speedup 1.0000x reference)
//
#include <hip/hip_runtime.h>

// MultiLabelEmbedding: mean-pooled embedding bag.
//  embed_table: float32 [100000, 32]   d_in[0]
//  indices:     int32   [16384, 50]    d_in[1]  (harness casts int64 -> int32)
//  lengths:     int32   [16384]        d_in[2]
//  out:         float32 [16384, 32]
//
// Structure: 8 lanes per bag, each lane owns one float4 (16B) of the 128B row.
// Each embedding-row read = one 128B coalesced transaction across 8 lanes.
// Table (12.8 MB) is L2/L3 resident -> gather-latency bound; 2048 waves give TLP.

#define BAGS      16384
#define BAG_LEN   50
#define EMB_DIM   32
#define LANES_PER_BAG 8   // 32 floats / 4 per float4

__global__ __launch_bounds__(256) void multilabel_embed_kernel(
    const float* __restrict__ table,
    const int*   __restrict__ indices,
    const int*   __restrict__ lengths,
    float*       __restrict__ out)
{
    const int tid = blockIdx.x * blockDim.x + threadIdx.x;
    const int bag = tid >> 3;          // 8 lanes per bag
    const int sub = tid & 7;           // which float4 of the row
    if (bag >= BAGS) return;

    int len = lengths[bag];
    if (len < 0) len = 0;
    if (len > BAG_LEN) len = BAG_LEN;

    const int* __restrict__ idx = indices + bag * BAG_LEN;

    float4 acc = make_float4(0.f, 0.f, 0.f, 0.f);
    for (int l = 0; l < len; ++l) {
        const int ix = idx[l];                         // broadcast across 8 lanes
        const float4 row = *reinterpret_cast<const float4*>(
            table + (size_t)ix * EMB_DIM + (sub << 2));
        acc.x += row.x; acc.y += row.y; acc.z += row.z; acc.w += row.w;
    }

    const float inv = 1.0f / (float)(len > 0 ? len : 1);
    acc.x *= inv; acc.y *= inv; acc.z *= inv; acc.w *= inv;

    *reinterpret_cast<float4*>(out + (size_t)bag * EMB_DIM + (sub << 2)) = acc;
}

extern "C" void kernel_launch(void* const* d_in, const int* in_sizes, int n_in,
                              void* d_out, int out_size, void* d_ws, size_t ws_size,
                              hipStream_t stream) {
    const float* table   = (const float*)d_in[0];
    const int*   indices = (const int*)d_in[1];
    const int*   lengths = (const int*)d_in[2];
    float*       out     = (float*)d_out;

    const int threads = 256;
    const int bagsPerBlock = threads / LANES_PER_BAG;          // 32
    const int grid = (BAGS + bagsPerBlock - 1) / bagsPerBlock; // 512

    multilabel_embed_kernel<<<grid, threads, 0, stream>>>(table, indices, lengths, out);
}

// Round 2
// 14.672 us; speedup vs baseline: 2.3598x; 2.3598x over previous
//
#include <hip/hip_runtime.h>

// MultiLabelEmbedding: mean-pooled embedding bag.
//  embed_table: float32 [100000, 32]   d_in[0]
//  indices:     int32   [16384, 50]    d_in[1]  (harness casts int64 -> int32)
//  lengths:     int32   [16384]        d_in[2]
//  out:         float32 [16384, 32]
//
// Round 2 structure:
//  - 32 lanes per bag, each lane owns ONE float of the 32-float row.
//    A row read = 32 lanes x 4B = 128B, one coalesced transaction; a wave
//    covers 2 bags. 16384*32/256 = 2048 blocks -> 8192 waves = 8 waves/SIMD
//    (occupancy cap) for latency hiding.
//  - Bag loop unrolled x8 with predication: indices[] is fully populated
//    (valid table rows even past `len`), so we clamp the offset and
//    zero-select the contribution -> 8 independent gathers in flight per
//    wave (MLP x8) instead of 1 dependent chain.

#define BAGS      16384
#define BAG_LEN   50
#define EMB_DIM   32
#define UNROLL    8

__global__ __launch_bounds__(256) void multilabel_embed_kernel(
    const float* __restrict__ table,
    const int*   __restrict__ indices,
    const int*   __restrict__ lengths,
    float*       __restrict__ out)
{
    const int tid = blockIdx.x * blockDim.x + threadIdx.x;
    const int bag = tid >> 5;          // 32 lanes per bag
    const int sub = tid & 31;          // which float of the row
    if (bag >= BAGS) return;

    int len = lengths[bag];
    if (len < 0) len = 0;
    if (len > BAG_LEN) len = BAG_LEN;

    const int* __restrict__ idx = indices + bag * BAG_LEN;

    float acc = 0.0f;
    for (int base = 0; base < len; base += UNROLL) {
        int ixs[UNROLL];
#pragma unroll
        for (int k = 0; k < UNROLL; ++k) {
            const int l = base + k;
            ixs[k] = idx[(l < len) ? l : 0];   // clamped offset: always in-bounds
        }
        float r[UNROLL];
#pragma unroll
        for (int k = 0; k < UNROLL; ++k) {
            r[k] = table[(size_t)ixs[k] * EMB_DIM + sub];   // 8 independent gathers
        }
#pragma unroll
        for (int k = 0; k < UNROLL; ++k) {
            acc += (base + k < len) ? r[k] : 0.0f;
        }
    }

    const float inv = 1.0f / (float)(len > 0 ? len : 1);
    out[(size_t)bag * EMB_DIM + sub] = acc * inv;
}

extern "C" void kernel_launch(void* const* d_in, const int* in_sizes, int n_in,
                              void* d_out, int out_size, void* d_ws, size_t ws_size,
                              hipStream_t stream) {
    const float* table   = (const float*)d_in[0];
    const int*   indices = (const int*)d_in[1];
    const int*   lengths = (const int*)d_in[2];
    float*       out     = (float*)d_out;

    const int threads = 256;
    const int lanesTotal = BAGS * 32;
    const int grid = (lanesTotal + threads - 1) / threads;   // 2048 blocks

    multilabel_embed_kernel<<<grid, threads, 0, stream>>>(table, indices, lengths, out);
}

// Round 3
// 14.669 us; speedup vs baseline: 2.3602x; 1.0002x over previous
//
#include <hip/hip_runtime.h>

// MultiLabelEmbedding: mean-pooled embedding bag.
//  embed_table: float32 [100000, 32]   d_in[0]
//  indices:     int32   [16384, 50]    d_in[1]
//  lengths:     int32   [16384]        d_in[2]
//  out:         float32 [16384, 32]
//
// Round 3 structure: ONE BAG PER WAVE.
//  - len is wave-uniform -> zero divergence waste (round 2 wasted ~34% on
//    max(len) over 2 bags/wave), scalar loop control.
//  - Lane layout: sub=(lane&7)*4 floats of the row, eg=lane>>3 in [0,8).
//    One global_load_dwordx4 gathers 8 embedding rows (1 KB) per instruction
//    -> ~4.7x fewer gather instructions than round 2, address VALU amortized.
//  - Loop steps 16 elements (2 independent dwordx4 gathers in flight).
//  - Epilogue: 3-level __shfl_xor (8/16/32) reduction over element groups,
//    lanes 0..7 store the 128B output row.

#define BAGS      16384
#define BAG_LEN   50
#define EMB_DIM   32

__global__ __launch_bounds__(256) void multilabel_embed_kernel(
    const float* __restrict__ table,
    const int*   __restrict__ indices,
    const int*   __restrict__ lengths,
    float*       __restrict__ out)
{
    const int wavesPerBlock = blockDim.x >> 6;                    // 4
    int bag = blockIdx.x * wavesPerBlock + (threadIdx.x >> 6);
    bag = __builtin_amdgcn_readfirstlane(bag);                    // wave-uniform
    if (bag >= BAGS) return;

    const int lane = threadIdx.x & 63;
    const int sub  = (lane & 7) << 2;   // float offset within the 32-float row
    const int eg   = lane >> 3;         // element group 0..7

    int len = lengths[bag];
    len = __builtin_amdgcn_readfirstlane(len);                    // scalar
    if (len < 0) len = 0;
    if (len > BAG_LEN) len = BAG_LEN;

    const int* __restrict__ idx = indices + bag * BAG_LEN;

    float4 acc = make_float4(0.f, 0.f, 0.f, 0.f);
    for (int base = 0; base < len; base += 16) {
        const int l0 = base + eg;
        const int l1 = base + 8 + eg;
        // clamped offsets: always load a real (hot) row, select-out below
        const int i0 = idx[(l0 < len) ? l0 : 0];
        const int i1 = idx[(l1 < len) ? l1 : 0];
        const float4 r0 = *reinterpret_cast<const float4*>(
            table + (size_t)i0 * EMB_DIM + sub);
        const float4 r1 = *reinterpret_cast<const float4*>(
            table + (size_t)i1 * EMB_DIM + sub);
        const bool v0 = (l0 < len), v1 = (l1 < len);
        acc.x += v0 ? r0.x : 0.f;  acc.y += v0 ? r0.y : 0.f;
        acc.z += v0 ? r0.z : 0.f;  acc.w += v0 ? r0.w : 0.f;
        acc.x += v1 ? r1.x : 0.f;  acc.y += v1 ? r1.y : 0.f;
        acc.z += v1 ? r1.z : 0.f;  acc.w += v1 ? r1.w : 0.f;
    }

    // reduce over element groups: lanes l, l^8, l^16, l^32 share `sub`
#pragma unroll
    for (int m = 8; m < 64; m <<= 1) {
        acc.x += __shfl_xor(acc.x, m);
        acc.y += __shfl_xor(acc.y, m);
        acc.z += __shfl_xor(acc.z, m);
        acc.w += __shfl_xor(acc.w, m);
    }

    if (eg == 0) {   // lanes 0..7 write the 128B output row
        const float inv = 1.0f / (float)(len > 0 ? len : 1);
        acc.x *= inv; acc.y *= inv; acc.z *= inv; acc.w *= inv;
        *reinterpret_cast<float4*>(out + (size_t)bag * EMB_DIM + sub) = acc;
    }
}

extern "C" void kernel_launch(void* const* d_in, const int* in_sizes, int n_in,
                              void* d_out, int out_size, void* d_ws, size_t ws_size,
                              hipStream_t stream) {
    const float* table   = (const float*)d_in[0];
    const int*   indices = (const int*)d_in[1];
    const int*   lengths = (const int*)d_in[2];
    float*       out     = (float*)d_out;

    const int threads = 256;                       // 4 waves = 4 bags per block
    const int grid = BAGS / 4;                     // 4096 blocks, 16384 waves

    multilabel_embed_kernel<<<grid, threads, 0, stream>>>(table, indices, lengths, out);
}